// Round 19
// baseline (41.700 us; speedup 1.0000x reference)
//
#include <hip/hip_runtime.h>

#define DIM 64
#define HID 512
#define BATCH 8192
#define MB 64      // samples per M-supertile; block = (mtile, half)
#define NTHR 1024  // 16 waves: 8 z-waves + 8 s-waves

typedef __attribute__((ext_vector_type(8))) short short8;
typedef __attribute__((ext_vector_type(4))) float f32x4;
typedef __attribute__((ext_vector_type(16))) float f32x16;
typedef float float4_ __attribute__((ext_vector_type(4)));
typedef unsigned long long ull;

#define Z16 {0.f,0.f,0.f,0.f,0.f,0.f,0.f,0.f,0.f,0.f,0.f,0.f,0.f,0.f,0.f,0.f}

union U8 { short8 s8; unsigned short u[8]; };
union U4 { ull v; unsigned short u[4]; };
union FB { unsigned u; float f; };

__device__ __forceinline__ unsigned short f2bf(float f) {
    union { float f; unsigned u; } v; v.f = f;
    return (unsigned short)((v.u + 0x7FFFu + ((v.u >> 16) & 1u)) >> 16);
}
__device__ __forceinline__ float bf2f(unsigned short b) {
    FB v; v.u = (unsigned)b << 16; return v.f;
}
__device__ __forceinline__ float tanh_fast(float x) {
    float e = __expf(2.f * x);
    return 1.f - __fdividef(2.f, e + 1.f);
}

// Packs W2, P, W3(half-K), W1 into bf16 MFMA fragments + c1 = b1 + t*W1[64,:].
__global__ __launch_bounds__(256) void prep(
        const float* __restrict__ t,  const float* __restrict__ W1,
        const float* __restrict__ b1, const float* __restrict__ W2,
        const float* __restrict__ W3,
        unsigned short* __restrict__ w2pk, unsigned short* __restrict__ ppk,
        unsigned short* __restrict__ w3pk, unsigned short* __restrict__ w1pk,
        float* __restrict__ c1) {
    __shared__ float w3sT[DIM * 33];     // 32-col W3^T slice, padded
    __shared__ float w1s[DIM * DIM];     // 64-col W1 slice
    int b = blockIdx.x;
    if (b >= 288) {   // c1 tail
        int n = (b - 288) * 256 + threadIdx.x;
        c1[n] = fmaf(t[0], W1[DIM * HID + n], b1[n]);
        return;
    }
    int gid = b * 256 + threadIdx.x;
    int f = gid >> 6, l = gid & 63;
    if (f < 512) {            // W2 frags: fi = nt*32+ks, k0 = ks*16+(l>>5)*8
        int nt = f >> 5, ks = f & 31;
        int n = nt * 32 + (l & 31), k0 = ks * 16 + (l >> 5) * 8;
        unsigned short* o = w2pk + (size_t)(f * 64 + l) * 8;
#pragma unroll
        for (int e = 0; e < 8; ++e) o[e] = f2bf(W2[(size_t)(k0 + e) * HID + n]);
    } else if (f < 1024) {    // P[j][n] = W2[j][n] * sum_i W1[i][j]*W3[n][i]
        int ntb = (b * 4 - 512) >> 5;            // block-uniform n-tile
        int jb  = (((b - 128) * 4) & 31) * 16;   // block-uniform 64-col W1 window
        for (int idx = threadIdx.x; idx < 32 * DIM; idx += 256) {
            int dn = idx >> 6, i = idx & 63;
            w3sT[i * 33 + dn] = W3[(size_t)(ntb * 32 + dn) * DIM + i];
        }
        for (int idx = threadIdx.x; idx < DIM * DIM; idx += 256) {
            int i = idx >> 6, jj = idx & 63;
            w1s[i * DIM + jj] = W1[(size_t)i * HID + jb + jj];
        }
        __syncthreads();
        int fi = f - 512;
        int ks = fi & 31;
        int dn = l & 31, k0 = ks * 16 + (l >> 5) * 8;   // j = k0+e (contraction)
        int n = ntb * 32 + dn;
        int jo = k0 - jb;
        float m[8] = {0.f,0.f,0.f,0.f,0.f,0.f,0.f,0.f};
#pragma unroll
        for (int i = 0; i < DIM; ++i) {
            float w3 = w3sT[i * 33 + dn];
            const float* wrow = &w1s[i * DIM + jo];
#pragma unroll
            for (int e = 0; e < 8; ++e) m[e] = fmaf(wrow[e], w3, m[e]);
        }
        unsigned short* o = ppk + (size_t)(fi * 64 + l) * 8;
#pragma unroll
        for (int e = 0; e < 8; ++e) o[e] = f2bf(W2[(size_t)(k0 + e) * HID + n] * m[e]);
    } else if (f < 1088) {    // W3 half-K frags: fi = half*32 + nt*8 + ks (validated in R7)
        int fi = f - 1024;
        int hf = fi >> 5, nt = (fi >> 3) & 3, ks = fi & 7;
        int n = nt * 16 + (l & 15), k0 = hf * 256 + ks * 32 + (l >> 4) * 8;
        unsigned short* o = w3pk + (size_t)(fi * 64 + l) * 8;
#pragma unroll
        for (int e = 0; e < 8; ++e) o[e] = f2bf(W3[(size_t)(k0 + e) * DIM + n]);
    } else {                  // W1 A-frags: fi = mt*2 + ks
        int fi = f - 1088;
        int nt = fi >> 1, ks = fi & 1;
        int n = nt * 16 + (l & 15), k0 = ks * 32 + (l >> 4) * 8;
        unsigned short* o = w1pk + (size_t)(fi * 64 + l) * 8;
#pragma unroll
        for (int e = 0; e < 8; ++e) o[e] = f2bf(W1[(size_t)(k0 + e) * HID + n]);
    }
}

// h1/d1 LDS tiles: [sample][col] bf16, pitch 1024B, byte ^= (sample&15)<<4
__device__ __forceinline__ int act_addr(int sample, int colbyte) {
    return (sample * 1024 + colbyte) ^ ((sample & 15) << 4);
}
// h2 LDS tile (aliased onto d1s): [sample][256 cols] bf16, pitch 512B
__device__ __forceinline__ int h2_addr(int sample, int colbyte) {
    return (sample * 512 + colbyte) ^ ((sample & 15) << 4);
}

__global__ __launch_bounds__(NTHR)
__attribute__((amdgpu_waves_per_eu(4, 4)))
void fused_main(
        const float* __restrict__ x,  const float* __restrict__ c1,
        const float* __restrict__ b2,
        const unsigned short* __restrict__ w1pk, const unsigned short* __restrict__ w2pk,
        const unsigned short* __restrict__ ppk,  const unsigned short* __restrict__ w3pk,
        float* __restrict__ wsv, float* __restrict__ wsdiv) {
    __shared__ unsigned short h1s[MB * HID];   // 64 KB
    __shared__ unsigned short d1s[MB * HID];   // 64 KB; first 32 KB reused as h2 after K-loop
    __shared__ float wred[8][MB];              // 2 KB
    char* h1b = (char*)h1s; char* d1b = (char*)d1s; char* h2b = (char*)d1s;

    const int tid = threadIdx.x, w = tid >> 6, l = tid & 63;
    const int lr = l & 15, g = l >> 4;
    const int bid = blockIdx.x;
    const int mtile = bid >> 1, half = bid & 1;
    const int s0 = mtile * MB;

    // ======== phase 1^T (16x16): h1,d1 for 64 samples x 512 cols ========
    short8 xf[4][2];   // [sample-tile][ks]
#pragma unroll
    for (int nt = 0; nt < 4; ++nt)
#pragma unroll
        for (int ks = 0; ks < 2; ++ks) {
            const float* xp = x + (size_t)(s0 + nt * 16 + lr) * DIM + ks * 32 + g * 8;
            float4_ x0 = *(const float4_*)xp;
            float4_ x1 = *(const float4_*)(xp + 4);
            U8 u;
            u.u[0]=f2bf(x0.x); u.u[1]=f2bf(x0.y); u.u[2]=f2bf(x0.z); u.u[3]=f2bf(x0.w);
            u.u[4]=f2bf(x1.x); u.u[5]=f2bf(x1.y); u.u[6]=f2bf(x1.z); u.u[7]=f2bf(x1.w);
            xf[nt][ks] = u.s8;
        }
#pragma unroll
    for (int mi = 0; mi < 2; ++mi) {
        int mt = w * 2 + mi;   // hid1-col 16-tile
        short8 a0 = ((const short8*)w1pk)[(size_t)((mt * 2 + 0) * 64 + l)];
        short8 a1 = ((const short8*)w1pk)[(size_t)((mt * 2 + 1) * 64 + l)];
        float c1q[4];
#pragma unroll
        for (int r = 0; r < 4; ++r) c1q[r] = c1[mt * 16 + g * 4 + r];
#pragma unroll
        for (int nt = 0; nt < 4; ++nt) {
            f32x4 acc = {0.f, 0.f, 0.f, 0.f};
            acc = __builtin_amdgcn_mfma_f32_16x16x32_bf16(a0, xf[nt][0], acc, 0, 0, 0);
            acc = __builtin_amdgcn_mfma_f32_16x16x32_bf16(a1, xf[nt][1], acc, 0, 0, 0);
            int sample = nt * 16 + lr;
            U4 hu, du;
#pragma unroll
            for (int r = 0; r < 4; ++r) {
                float h = tanh_fast(acc[r] + c1q[r]);
                hu.u[r] = f2bf(h);
                du.u[r] = f2bf(fmaf(-h, h, 1.f));
            }
            int ab = act_addr(sample, (mt * 16 + g * 4) * 2);
            *(ull*)(h1b + ab) = hu.v;
            *(ull*)(d1b + ab) = du.v;
        }
    }
    __syncthreads();

    // ======== phase 2 (32x32x16), role-split, N-half only ========
    // z-waves (w<8): h1@W2[half];  s-waves: d1@P[half].  Wave q: local n-tile q, 2 row-tiles.
    const int q = w & 7, role = w >> 3;
    const int ntg = half * 8 + q;   // global 32-col weight tile
    const short8* Bs = (const short8*)(role ? ppk : w2pk) + (size_t)(ntg * 32) * 64 + l;
    const char* Ab = role ? d1b : h1b;
    const int rot = (bid * 5) & 31;
    f32x16 aA = Z16, aB = Z16;      // row-tiles: samples 0-31, 32-63
#pragma unroll 4
    for (int i = 0; i < 32; ++i) {
        int ks = (i + rot) & 31;
        int cb = ks * 32 + (l >> 5) * 16;
        short8 bv = Bs[ks * 64];
        short8 fA = *(const short8*)(Ab + act_addr(l & 31, cb));
        short8 fB = *(const short8*)(Ab + act_addr(32 + (l & 31), cb));
        aA = __builtin_amdgcn_mfma_f32_32x32x16_bf16(fA, bv, aA, 0, 0, 0);
        aB = __builtin_amdgcn_mfma_f32_32x32x16_bf16(fB, bv, aB, 0, 0, 0);
    }
    __syncthreads();   // all h1/d1 K-loop reads done (h2 overwrites d1s area)

    // z-waves: h2 = tanh(z + b2) -> h2 image (aliased LDS)
    if (role == 0) {
        int lc = q * 32 + (l & 31);          // local col 0..255
        float b2v = b2[half * 256 + lc];
#pragma unroll
        for (int j = 0; j < 2; ++j) {
            f32x16 acc = j ? aB : aA;
#pragma unroll
            for (int r = 0; r < 16; ++r) {
                int sample = j * 32 + (r & 3) + 8 * (r >> 2) + 4 * (l >> 5);
                *(unsigned short*)(h2b + h2_addr(sample, lc * 2)) =
                    f2bf(tanh_fast(acc[r] + b2v));
            }
        }
    }
    __syncthreads();   // h2 ready

    if (role == 1) {
        // s-waves: div partials over own 32 cols (sum over halves done in reduce_k)
        int lc = q * 32 + (l & 31);
#pragma unroll
        for (int j = 0; j < 2; ++j) {
            f32x16 acc = j ? aB : aA;
            float dp[16];
#pragma unroll
            for (int r = 0; r < 16; ++r) {
                int rm = (r & 3) + 8 * (r >> 2) + 4 * (l >> 5);
                float h2 = bf2f(*(const unsigned short*)(h2b + h2_addr(j * 32 + rm, lc * 2)));
                dp[r] = acc[r] * fmaf(-h2, h2, 1.f);
            }
#pragma unroll
            for (int off = 1; off < 32; off <<= 1) {
#pragma unroll
                for (int r = 0; r < 16; ++r) dp[r] += __shfl_xor(dp[r], off, 64);
            }
            if ((l & 31) == 0) {
#pragma unroll
                for (int r = 0; r < 16; ++r) {
                    int rm = (r & 3) + 8 * (r >> 2) + 4 * (l >> 5);
                    wred[q][j * 32 + rm] = dp[r];
                }
            }
        }
    } else {
        // z-waves: split-K phase 3: v-partial = h2_half @ W3_half -> wsv
#pragma unroll
        for (int jj = 0; jj < 2; ++jj) {
            int p = q * 2 + jj, mt = p >> 2, ntv = p & 3;
            f32x4 acc3 = {0.f, 0.f, 0.f, 0.f};
            const short8* W3f = (const short8*)w3pk + (size_t)((half * 32 + ntv * 8) * 64) + l;
#pragma unroll
            for (int ks = 0; ks < 8; ++ks) {
                short8 ah = *(const short8*)(h2b + h2_addr(mt * 16 + lr, ks * 64 + g * 16));
                acc3 = __builtin_amdgcn_mfma_f32_16x16x32_bf16(ah, W3f[ks * 64], acc3, 0, 0, 0);
            }
#pragma unroll
            for (int r = 0; r < 4; ++r)
                wsv[(size_t)bid * 4096 + (mt * 16 + g * 4 + r) * 64 + ntv * 16 + lr] = acc3[r];
        }
    }
    __syncthreads();   // wred complete
    if (tid < MB) {
        float d = 0.f;
#pragma unroll
        for (int ww = 0; ww < 8; ++ww) d += wred[ww][tid];
        wsdiv[bid * 64 + tid] = d;
    }
}

// combine split-K v partials (+b3) and div partials (negate)
__global__ __launch_bounds__(1024) void reduce_k(
        const float* __restrict__ wsv, const float* __restrict__ wsdiv,
        const float* __restrict__ b3, float* __restrict__ out) {
    int idx = blockIdx.x * 1024 + threadIdx.x;   // 0 .. 8192*64-1
    int sample = idx >> 6, dcol = idx & 63;
    int m = sample >> 6, sl = sample & 63;
    float v = wsv[(size_t)(2 * m) * 4096 + sl * 64 + dcol]
            + wsv[(size_t)(2 * m + 1) * 4096 + sl * 64 + dcol] + b3[dcol];
    out[idx] = v;
    if (idx < BATCH) {
        int m2 = idx >> 6, sl2 = idx & 63;
        out[(size_t)BATCH * DIM + idx] =
            -(wsdiv[(2 * m2) * 64 + sl2] + wsdiv[(2 * m2 + 1) * 64 + sl2]);
    }
}

extern "C" void kernel_launch(void* const* d_in, const int* in_sizes, int n_in,
                              void* d_out, int out_size, void* d_ws, size_t ws_size,
                              hipStream_t stream) {
    const float* t  = (const float*)d_in[0];
    const float* x  = (const float*)d_in[1];
    const float* W1 = (const float*)d_in[2];
    const float* b1 = (const float*)d_in[3];
    const float* W2 = (const float*)d_in[4];
    const float* b2 = (const float*)d_in[5];
    const float* W3 = (const float*)d_in[6];
    const float* b3 = (const float*)d_in[7];
    float* out = (float*)d_out;

    char* ws = (char*)d_ws;
    unsigned short* w2pk = (unsigned short*)ws;                             // 512 KB
    unsigned short* ppk  = (unsigned short*)(ws + (512 << 10));             // 512 KB
    unsigned short* w3pk = (unsigned short*)(ws + (1 << 20));               // 64 KB
    unsigned short* w1pk = (unsigned short*)(ws + (1 << 20) + (64 << 10));  // 64 KB
    float*          c1   = (float*)(ws + (1 << 20) + (128 << 10));          // 2 KB
    float*          wsv  = (float*)(ws + (1 << 20) + (192 << 10));          // 4 MB
    float*          wsdiv= (float*)(ws + (1 << 20) + (192 << 10) + (4 << 20)); // 64 KB

    prep      <<<290, 256, 0, stream>>>(t, W1, b1, W2, W3, w2pk, ppk, w3pk, w1pk, c1);
    fused_main<<<(BATCH / MB) * 2, NTHR, 0, stream>>>(x, c1, b2, w1pk, w2pk, ppk, w3pk, wsv, wsdiv);
    reduce_k  <<<(BATCH * DIM) / 1024, 1024, 0, stream>>>(wsv, wsdiv, b3, out);
}

// Round 20
// 35.276 us; speedup vs baseline: 1.1821x; 1.1821x over previous
//
#include <hip/hip_runtime.h>

#define DIM 64
#define HID 512
#define BATCH 8192
#define MB 32      // samples per block
#define NTHR 1024  // 16 waves: 8 z-waves + 8 s-waves

typedef __attribute__((ext_vector_type(8))) short short8;
typedef __attribute__((ext_vector_type(4))) float f32x4;
typedef __attribute__((ext_vector_type(16))) float f32x16;
typedef float float4_ __attribute__((ext_vector_type(4)));
typedef unsigned long long ull;

#define Z16 {0.f,0.f,0.f,0.f,0.f,0.f,0.f,0.f,0.f,0.f,0.f,0.f,0.f,0.f,0.f,0.f}

union U8 { short8 s8; unsigned short u[8]; };
union U4 { ull v; unsigned short u[4]; };
union FB { unsigned u; float f; };

__device__ __forceinline__ unsigned short f2bf(float f) {
    union { float f; unsigned u; } v; v.f = f;
    return (unsigned short)((v.u + 0x7FFFu + ((v.u >> 16) & 1u)) >> 16);
}
__device__ __forceinline__ float bf2f(unsigned short b) {
    FB v; v.u = (unsigned)b << 16; return v.f;
}
__device__ __forceinline__ float tanh_fast(float x) {
    float e = __expf(2.f * x);
    return 1.f - __fdividef(2.f, e + 1.f);
}
// async 16B global -> LDS (dest: wave-uniform base + lane*16; src: per-lane)
__device__ __forceinline__ void gl_lds16(const void* g, void* l) {
    __builtin_amdgcn_global_load_lds(
        (const __attribute__((address_space(1))) unsigned*)g,
        (__attribute__((address_space(3))) unsigned*)l, 16, 0, 0);
}

// Packs W2, P, W3, W1 into bf16 MFMA fragments + c1 = b1 + t*W1[64,:].
__global__ __launch_bounds__(256) void prep(
        const float* __restrict__ t,  const float* __restrict__ W1,
        const float* __restrict__ b1, const float* __restrict__ W2,
        const float* __restrict__ W3,
        unsigned short* __restrict__ w2pk, unsigned short* __restrict__ ppk,
        unsigned short* __restrict__ w3pk, unsigned short* __restrict__ w1pk,
        float* __restrict__ c1) {
    __shared__ float w3sT[DIM * 33];     // 32-col W3^T slice, padded
    __shared__ float w1s[DIM * DIM];     // 64-col W1 slice
    int b = blockIdx.x;
    if (b >= 288) {   // c1 tail
        int n = (b - 288) * 256 + threadIdx.x;
        c1[n] = fmaf(t[0], W1[DIM * HID + n], b1[n]);
        return;
    }
    int gid = b * 256 + threadIdx.x;
    int f = gid >> 6, l = gid & 63;
    if (f < 512) {            // W2 frags
        int nt = f >> 5, ks = f & 31;
        int n = nt * 32 + (l & 31), k0 = ks * 16 + (l >> 5) * 8;
        unsigned short* o = w2pk + (size_t)(f * 64 + l) * 8;
#pragma unroll
        for (int e = 0; e < 8; ++e) o[e] = f2bf(W2[(size_t)(k0 + e) * HID + n]);
    } else if (f < 1024) {    // P[j][n] = W2[j][n] * sum_i W1[i][j]*W3[n][i]
        int ntb = (b * 4 - 512) >> 5;            // block-uniform n-tile
        int jb  = (((b - 128) * 4) & 31) * 16;   // block-uniform 64-col W1 window
        for (int idx = threadIdx.x; idx < 32 * DIM; idx += 256) {
            int dn = idx >> 6, i = idx & 63;
            w3sT[i * 33 + dn] = W3[(size_t)(ntb * 32 + dn) * DIM + i];
        }
        for (int idx = threadIdx.x; idx < DIM * DIM; idx += 256) {
            int i = idx >> 6, jj = idx & 63;
            w1s[i * DIM + jj] = W1[(size_t)i * HID + jb + jj];
        }
        __syncthreads();
        int fi = f - 512;
        int ks = fi & 31;
        int dn = l & 31, k0 = ks * 16 + (l >> 5) * 8;   // j = k0+e (contraction)
        int n = ntb * 32 + dn;
        int jo = k0 - jb;
        float m[8] = {0.f,0.f,0.f,0.f,0.f,0.f,0.f,0.f};
#pragma unroll
        for (int i = 0; i < DIM; ++i) {
            float w3 = w3sT[i * 33 + dn];
            const float* wrow = &w1s[i * DIM + jo];
#pragma unroll
            for (int e = 0; e < 8; ++e) m[e] = fmaf(wrow[e], w3, m[e]);
        }
        unsigned short* o = ppk + (size_t)(fi * 64 + l) * 8;
#pragma unroll
        for (int e = 0; e < 8; ++e) o[e] = f2bf(W2[(size_t)(k0 + e) * HID + n] * m[e]);
    } else if (f < 1088) {    // W3 frags (N=64): fi = nt*16 + ks
        int fi = f - 1024;
        int nt = fi >> 4, ks = fi & 15;
        int n = nt * 16 + (l & 15), k0 = ks * 32 + (l >> 4) * 8;
        unsigned short* o = w3pk + (size_t)(fi * 64 + l) * 8;
#pragma unroll
        for (int e = 0; e < 8; ++e) o[e] = f2bf(W3[(size_t)(k0 + e) * DIM + n]);
    } else {                  // W1 A-frags: fi = mt*2 + ks
        int fi = f - 1088;
        int nt = fi >> 1, ks = fi & 1;
        int n = nt * 16 + (l & 15), k0 = ks * 32 + (l >> 4) * 8;
        unsigned short* o = w1pk + (size_t)(fi * 64 + l) * 8;
#pragma unroll
        for (int e = 0; e < 8; ++e) o[e] = f2bf(W1[(size_t)(k0 + e) * HID + n]);
    }
}

// LDS activation tiles: [sample][col] bf16, pitch 1024B, byte ^= (sample&15)<<4
__device__ __forceinline__ int act_addr(int sample, int colbyte) {
    return (sample * 1024 + colbyte) ^ ((sample & 15) << 4);
}

__global__ __launch_bounds__(NTHR)
__attribute__((amdgpu_waves_per_eu(4, 4)))
void fused_main(
        const float* __restrict__ x,  const float* __restrict__ c1,
        const float* __restrict__ b2, const float* __restrict__ b3,
        const unsigned short* __restrict__ w1pk, const unsigned short* __restrict__ w2pk,
        const unsigned short* __restrict__ ppk,  const unsigned short* __restrict__ w3pk,
        float* __restrict__ out) {
    __shared__ unsigned short h1s[MB * HID];      // 32 KB
    __shared__ unsigned short d1s[MB * HID];      // 32 KB
    __shared__ unsigned short stage[2 * 16 * 2 * 512];  // 64 KB weight staging; first 32 KB reused as h2
    __shared__ float wred[8][MB];                 // 2 KB   (total 130 KB)
    char* h1b = (char*)h1s; char* d1b = (char*)d1s;
    char* stageb = (char*)stage; char* h2b = (char*)stage;

    const int tid = threadIdx.x, w = tid >> 6, l = tid & 63;
    const int lr = l & 15, g = l >> 4;
    const int s0 = blockIdx.x * MB;

    // ======== phase 1^T (16x16): h1 = tanh(W1^T x^T + c1), d1 = 1-h1^2 ========
    short8 xf[2][2];
#pragma unroll
    for (int nt = 0; nt < 2; ++nt)
#pragma unroll
        for (int ks = 0; ks < 2; ++ks) {
            const float* xp = x + (size_t)(s0 + nt * 16 + lr) * DIM + ks * 32 + g * 8;
            float4_ x0 = *(const float4_*)xp;
            float4_ x1 = *(const float4_*)(xp + 4);
            U8 u;
            u.u[0]=f2bf(x0.x); u.u[1]=f2bf(x0.y); u.u[2]=f2bf(x0.z); u.u[3]=f2bf(x0.w);
            u.u[4]=f2bf(x1.x); u.u[5]=f2bf(x1.y); u.u[6]=f2bf(x1.z); u.u[7]=f2bf(x1.w);
            xf[nt][ks] = u.s8;
        }
#pragma unroll
    for (int mi = 0; mi < 2; ++mi) {
        int mt = w * 2 + mi;
        short8 a0 = ((const short8*)w1pk)[(size_t)((mt * 2 + 0) * 64 + l)];
        short8 a1 = ((const short8*)w1pk)[(size_t)((mt * 2 + 1) * 64 + l)];
        float c1q[4];
#pragma unroll
        for (int r = 0; r < 4; ++r) c1q[r] = c1[mt * 16 + g * 4 + r];
#pragma unroll
        for (int nt = 0; nt < 2; ++nt) {
            f32x4 acc = {0.f, 0.f, 0.f, 0.f};
            acc = __builtin_amdgcn_mfma_f32_16x16x32_bf16(a0, xf[nt][0], acc, 0, 0, 0);
            acc = __builtin_amdgcn_mfma_f32_16x16x32_bf16(a1, xf[nt][1], acc, 0, 0, 0);
            int sample = nt * 16 + lr;
            U4 hu, du;
#pragma unroll
            for (int r = 0; r < 4; ++r) {
                float h = tanh_fast(acc[r] + c1q[r]);
                hu.u[r] = f2bf(h);
                du.u[r] = f2bf(fmaf(-h, h, 1.f));
            }
            int ab = act_addr(sample, (mt * 16 + g * 4) * 2);
            *(ull*)(h1b + ab) = hu.v;
            *(ull*)(d1b + ab) = du.v;
        }
    }
    __syncthreads();   // also drains vmcnt to 0 (barrier semantics) — counting starts clean

    // ======== phase 2 (32x32x16) ROLE-SPLIT + async global_load_lds B-staging ========
    // wave (q,role) owns n-tiles {2q,2q+1}; 2-deep double-buffer, counted vmcnt(2).
    const int q = w & 7, role = w >> 3;
    const char* Bf = (const char*)(role ? ppk : w2pk);
    const char* Ab = role ? d1b : h1b;
    // stage slot for (buf, wave, j): 1 KB each
#define SLOT(buf, j) (stageb + (((buf) * 16 + w) * 2 + (j)) * 1024)
#define ISSUE(buf, ks)                                                          \
    {                                                                           \
        gl_lds16(Bf + ((size_t)((2 * q + 0) * 32 + (ks)) * 64 + l) * 16, SLOT(buf, 0)); \
        gl_lds16(Bf + ((size_t)((2 * q + 1) * 32 + (ks)) * 64 + l) * 16, SLOT(buf, 1)); \
    }
    ISSUE(0, 0)
    ISSUE(1, 1)
    f32x16 a0 = Z16, a1 = Z16;
#pragma unroll
    for (int ks = 0; ks < 32; ++ks) {
        const int buf = ks & 1;
        if (ks == 31) { asm volatile("s_waitcnt vmcnt(0)" ::: "memory"); }
        else          { asm volatile("s_waitcnt vmcnt(2)" ::: "memory"); }
        __builtin_amdgcn_sched_barrier(0);
        short8 b0v = *(const short8*)(SLOT(buf, 0) + l * 16);
        short8 b1v = *(const short8*)(SLOT(buf, 1) + l * 16);
        short8 av  = *(const short8*)(Ab + act_addr(l & 31, ks * 32 + (l >> 5) * 16));
        a0 = __builtin_amdgcn_mfma_f32_32x32x16_bf16(av, b0v, a0, 0, 0, 0);
        a1 = __builtin_amdgcn_mfma_f32_32x32x16_bf16(av, b1v, a1, 0, 0, 0);
        if (ks + 2 < 32) {
            asm volatile("s_waitcnt lgkmcnt(0)" ::: "memory");  // b-reads done before overwrite
            __builtin_amdgcn_sched_barrier(0);
            ISSUE(buf, ks + 2)
        }
    }
#undef ISSUE
#undef SLOT
    __syncthreads();   // all staging reads done -> stage reusable as h2

    // z-waves: h2 = tanh(z + b2) -> h2 image (aliased onto stage)
    if (role == 0) {
#pragma unroll
        for (int j = 0; j < 2; ++j) {
            int c = (2 * q + j) * 32 + (l & 31);
            float b2v = b2[c];
            f32x16 acc = j ? a1 : a0;
#pragma unroll
            for (int r = 0; r < 16; ++r) {
                int row = (r & 3) + 8 * (r >> 2) + 4 * (l >> 5);
                *(unsigned short*)(h2b + act_addr(row, c * 2)) = f2bf(tanh_fast(acc[r] + b2v));
            }
        }
    }
    __syncthreads();   // h2 complete

    if (role == 1) {
        // s-waves: div partials; overlaps with z-waves' phase 3
        float divp[16];
#pragma unroll
        for (int r = 0; r < 16; ++r) divp[r] = 0.f;
#pragma unroll
        for (int j = 0; j < 2; ++j) {
            int c = (2 * q + j) * 32 + (l & 31);
            f32x16 acc = j ? a1 : a0;
#pragma unroll
            for (int r = 0; r < 16; ++r) {
                int row = (r & 3) + 8 * (r >> 2) + 4 * (l >> 5);
                float h2 = bf2f(*(const unsigned short*)(h2b + act_addr(row, c * 2)));
                divp[r] = fmaf(acc[r], fmaf(-h2, h2, 1.f), divp[r]);
            }
        }
#pragma unroll
        for (int off = 1; off < 32; off <<= 1) {
#pragma unroll
            for (int r = 0; r < 16; ++r) divp[r] += __shfl_xor(divp[r], off, 64);
        }
        if ((l & 31) == 0) {
#pragma unroll
            for (int r = 0; r < 16; ++r) {
                int row = (r & 3) + 8 * (r >> 2) + 4 * (l >> 5);
                wred[q][row] = divp[r];
            }
        }
    } else {
        // z-waves: phase 3 (16x16): v = h2 @ W3 + b3
        const int wm3 = w & 1, wn3 = w >> 1;
        f32x4 acc = {0.f, 0.f, 0.f, 0.f};
        const short8* W3f = (const short8*)w3pk + (size_t)(wn3 * 16) * 64 + l;
#pragma unroll
        for (int ks = 0; ks < 16; ++ks) {
            short8 ah = *(const short8*)(h2b + act_addr(wm3 * 16 + lr, ks * 64 + g * 16));
            acc = __builtin_amdgcn_mfma_f32_16x16x32_bf16(ah, W3f[ks * 64], acc, 0, 0, 0);
        }
        int c = wn3 * 16 + lr;
        float b3v = b3[c];
#pragma unroll
        for (int r = 0; r < 4; ++r)
            out[(size_t)(s0 + wm3 * 16 + g * 4 + r) * DIM + c] = acc[r] + b3v;
    }
    __syncthreads();   // wred complete
    if (tid < MB) {
        float d = 0.f;
#pragma unroll
        for (int ww = 0; ww < 8; ++ww) d += wred[ww][tid];
        out[(size_t)BATCH * DIM + s0 + tid] = -d;
    }
}

extern "C" void kernel_launch(void* const* d_in, const int* in_sizes, int n_in,
                              void* d_out, int out_size, void* d_ws, size_t ws_size,
                              hipStream_t stream) {
    const float* t  = (const float*)d_in[0];
    const float* x  = (const float*)d_in[1];
    const float* W1 = (const float*)d_in[2];
    const float* b1 = (const float*)d_in[3];
    const float* W2 = (const float*)d_in[4];
    const float* b2 = (const float*)d_in[5];
    const float* W3 = (const float*)d_in[6];
    const float* b3 = (const float*)d_in[7];
    float* out = (float*)d_out;

    char* ws = (char*)d_ws;
    unsigned short* w2pk = (unsigned short*)ws;                            // 512 KB
    unsigned short* ppk  = (unsigned short*)(ws + (512 << 10));            // 512 KB
    unsigned short* w3pk = (unsigned short*)(ws + (1 << 20));              // 64 KB
    unsigned short* w1pk = (unsigned short*)(ws + (1 << 20) + (64 << 10)); // 64 KB
    float*          c1   = (float*)(ws + (1 << 20) + (128 << 10));         // 2 KB

    prep<<<290, 256, 0, stream>>>(t, W1, b1, W2, W3, w2pk, ppk, w3pk, w1pk, c1);
    fused_main<<<BATCH / MB, NTHR, 0, stream>>>(x, c1, b2, b3, w1pk, w2pk, ppk, w3pk, out);
}